// Round 11
// baseline (6268.997 us; speedup 1.0000x reference)
//
#include <hip/hip_runtime.h>

// Problem constants (fixed by the reference).
#define TSTEPS 256
#define NNODE  100000
#define NEDGE  8192
#define KBLK   16                    // persistent-scan blocks (co-resident)
#define NTHR   1024
#define EPB    (NEDGE / KBLK)        // 512 edges per block in phase G

static_assert(KBLK * NTHR == 2 * NEDGE, "C-phase slot math requires K*T == 2E");

constexpr float MU_P  = 0.1f;
constexpr float MU_M  = 0.05f;
constexpr float RHO_  = 16.0f;
constexpr float CLO   = 1e-5f;
constexpr float CHI   = 1.0f - 1e-5f;
constexpr float SCALE = 1048576.0f;          // 2^20 fixed-point for delta
constexpr float INVSC = 1.0f / 1048576.0f;

// f32 sentinel: real X values are positive finite, 0xFFFFFFFF impossible.
#define SENT32 0xFFFFFFFFu

__device__ __forceinline__ float sigm(float x) {
  return 1.0f / (1.0f + __expf(-x));
}
__device__ __forceinline__ float x0_of(const float* logit, int n) {
  return fminf(fmaxf(sigm(logit[n]), CLO), CHI);
}
__device__ __forceinline__ int edge_at(const int* __restrict__ arr, int idx,
                                       int is64) {
  if (is64) return (int)((const long long*)arr)[idx];
  return arr[idx];
}

// Agent-scope (L3-coherent, L2-bypassing) helpers — the whole point: shared
// state NEVER lives in an incoherent per-XCD L2, so NO fences are needed.
__device__ __forceinline__ float aloadf(const float* p) {
  return __hip_atomic_load(p, __ATOMIC_RELAXED, __HIP_MEMORY_SCOPE_AGENT);
}
__device__ __forceinline__ void astoref(float* p, float v) {
  __hip_atomic_store(p, v, __ATOMIC_RELAXED, __HIP_MEMORY_SCOPE_AGENT);
}
__device__ __forceinline__ unsigned aloadu(const unsigned* p) {
  return __hip_atomic_load(p, __ATOMIC_RELAXED, __HIP_MEMORY_SCOPE_AGENT);
}
__device__ __forceinline__ void astoreu(unsigned* p, unsigned v) {
  __hip_atomic_store(p, v, __ATOMIC_RELAXED, __HIP_MEMORY_SCOPE_AGENT);
}
__device__ __forceinline__ void aaddu(unsigned* p, unsigned v) {
  __hip_atomic_fetch_add(p, v, __ATOMIC_RELAXED, __HIP_MEMORY_SCOPE_AGENT);
}

// ---------------------------------------------------------------------------
// k_detect: int32 vs int64 materialization of u/v (runtime-proof either way).
// ---------------------------------------------------------------------------
__global__ void k_detect(const int* __restrict__ u, const int* __restrict__ v,
                         unsigned* __restrict__ dflags) {
  if (threadIdx.x != 0 || blockIdx.x != 0) return;
  const unsigned* a = (const unsigned*)u;
  const unsigned* b = (const unsigned*)v;
  bool i64 = true;
  for (int k = 1; k < 128; k += 2) i64 = i64 && (a[k] == 0u) && (b[k] == 0u);
  dflags[0] = i64 ? 1u : 0u;
}

// ---------------------------------------------------------------------------
// k_init: both xs ping-pong buffers = clip(sigmoid(logit)); both deltas
// zeroed; barrier zeroed; output X row 0 = sigmoid(logit) UNCLIPPED f32;
// X rows 1..T-1 = sentinel. Re-runs every call -> deterministic replays.
// ---------------------------------------------------------------------------
__global__ void k_init(const float* __restrict__ logit,
                       float* __restrict__ xsA, float* __restrict__ xsB,
                       unsigned* __restrict__ dA, unsigned* __restrict__ dB,
                       unsigned* __restrict__ bar,
                       float* __restrict__ outX) {
  const int i = blockIdx.x * blockDim.x + threadIdx.x;
  const int stride = gridDim.x * blockDim.x;

  for (int n = i; n < NNODE; n += stride) {
    const float x0c = x0_of(logit, n);
    xsA[n] = x0c;
    xsB[n] = x0c;
    dA[n]  = 0u;
    dB[n]  = 0u;
    outX[n] = sigm(logit[n]);            // row 0, unclipped, f32
  }
  unsigned* outX32 = (unsigned*)outX;
  const int total = TSTEPS * NNODE;
  for (int w = NNODE + i; w < total; w += stride) outX32[w] = SENT32;
  if (i < 2) bar[i] = 0u;
}

// ---------------------------------------------------------------------------
// Fence-free global barrier: monotone arrival counter at the L3 coherence
// point. No reset, no release store -> no store-ordering hazard. Prior work
// is drained by __syncthreads (compiler emits s_waitcnt vmcnt(0) before
// s_barrier), and ALL shared state is agent-scope (performed at L3), so a
// block that observes count >= K*gen also observes all phase writes.
// ---------------------------------------------------------------------------
__device__ __forceinline__ void gbar(unsigned* bar, unsigned* gen) {
  __syncthreads();
  if (threadIdx.x == 0) {
    ++(*gen);
    __hip_atomic_fetch_add(&bar[0], 1u, __ATOMIC_RELAXED,
                           __HIP_MEMORY_SCOPE_AGENT);
    const unsigned need = (unsigned)KBLK * (*gen);
    while (__hip_atomic_load(&bar[0], __ATOMIC_RELAXED,
                             __HIP_MEMORY_SCOPE_AGENT) < need) {
      __builtin_amdgcn_s_sleep(1);
    }
  }
  __syncthreads();
}

// ---------------------------------------------------------------------------
// k_scan: 255-step scan, ONE persistent dispatch, claim-free ping-pong.
//   R = bufs[t&1] holds complete x_t; W = bufs[(t+1)&1] holds complete
//   x_{t-1} at phase-C entry.
//   G: 512 edges/block: gather R, accumulate fixed-point delta dC=d[t&1].
//   C: 2048 slots/block over endpoints(t) ++ endpoints(t-1):
//      val = clip(R[n] + dC[n])   (identical for every duplicate writer ->
//      benign races, no claim); write W[n] and outX[t+1][n]; slots of
//      endpoints(t-1) also zero dP=d[(t+1)&1] (unused this step) so it is
//      a clean accumulator for step t+1.
//   After C, W holds complete x_{t+1} (touched(t): new val; touched(t-1):
//   val=x_t since dC=0 there; rest: x_{t-1}=x_t=x_{t+1} untouched).
// ---------------------------------------------------------------------------
__global__ __launch_bounds__(NTHR, 1) void k_scan(
    const int* __restrict__ u, const int* __restrict__ v,
    const float* __restrict__ sp, const float* __restrict__ sm,
    float* __restrict__ xsA, float* __restrict__ xsB,
    unsigned* __restrict__ dA, unsigned* __restrict__ dB,
    unsigned* __restrict__ bar, const unsigned* __restrict__ dflags,
    float* __restrict__ outX) {
  const int tid  = threadIdx.x;
  const int bid  = blockIdx.x;
  const int is64 = (int)dflags[0];
  unsigned gen = 0;

  float*    bufs[2] = {xsA, xsB};
  unsigned* ds[2]   = {dA, dB};

  for (int t = 0; t < TSTEPS - 1; ++t) {
    float*    R  = bufs[t & 1];
    float*    W  = bufs[(t + 1) & 1];
    unsigned* dC = ds[t & 1];
    unsigned* dP = ds[(t + 1) & 1];   // zeroed accumulator for step t+1

    // ---- Phase G: accumulate this step's delta from R ----
    if (tid < EPB) {
      const int e  = t * NEDGE + bid * EPB + tid;   // coalesced
      const int un = edge_at(u, e, is64);
      const int vn = edge_at(v, e, is64);
      const float xu = aloadf(&R[un]);
      const float xv = aloadf(&R[vn]);
      const float w  = MU_P * sp[e] - MU_M * sm[e];
      const int   iv = __float2int_rn(w * (xv - xu) * SCALE);
      aaddu(&dC[un], (unsigned)iv);
      aaddu(&dC[vn], (unsigned)(-iv));
    }
    gbar(bar, &gen);

    // ---- Phase C: materialize x_{t+1} into W; scatter output row t+1 ----
    for (int k = 0; k < 2; ++k) {
      const int s = bid * (2 * NTHR) + k * NTHR + tid;    // 0..32767
      int node;
      bool zero_dp = false;
      if (s < 2 * NEDGE) {                 // endpoints of step t
        node = (s < NEDGE) ? edge_at(u, t * NEDGE + s, is64)
                           : edge_at(v, t * NEDGE + s - NEDGE, is64);
      } else {                             // endpoints of step t-1
        if (t == 0) continue;
        const int s2 = s - 2 * NEDGE;
        node = (s2 < NEDGE) ? edge_at(u, (t - 1) * NEDGE + s2, is64)
                            : edge_at(v, (t - 1) * NEDGE + s2 - NEDGE, is64);
        zero_dp = true;
      }
      const float base = aloadf(&R[node]);
      const int   acc  = (int)aloadu(&dC[node]);
      const float val  = fminf(fmaxf(base + (float)acc * INVSC, CLO), CHI);
      astoref(&W[node], val);
      outX[(size_t)(t + 1) * NNODE + node] = val;   // duplicates: same value
      if (zero_dp) astoreu(&dP[node], 0u);
    }
    gbar(bar, &gen);
  }
}

// ---------------------------------------------------------------------------
// k_fill: resolve sentinels by fill-forward; coalesced per-node columns.
// ---------------------------------------------------------------------------
__global__ void k_fill(const float* __restrict__ logit,
                       unsigned* __restrict__ outX32) {
  const int n = blockIdx.x * blockDim.x + threadIdx.x;
  if (n >= NNODE) return;
  unsigned carry = __float_as_uint(x0_of(logit, n));   // untouched = clip(X0)
  for (int t = 1; t < TSTEPS; ++t) {
    const size_t idx = (size_t)t * NNODE + n;
    const unsigned w = outX32[idx];
    if (w == SENT32) outX32[idx] = carry;
    else             carry = w;
  }
}

// ---------------------------------------------------------------------------
// k_kappa: massively-parallel kappa over ALL T*E edges from the filled dense
// X (f32, exact scan values). Removed from the sequential critical path.
// ---------------------------------------------------------------------------
__global__ void k_kappa(const int* __restrict__ u, const int* __restrict__ v,
                        const float* __restrict__ theta,
                        const float* __restrict__ X,
                        float* __restrict__ outKp, float* __restrict__ outKm,
                        const unsigned* __restrict__ dflags) {
  const int g = blockIdx.x * blockDim.x + threadIdx.x;   // 0..T*E-1
  const int is64 = (int)dflags[0];
  const int t  = g >> 13;                                // / NEDGE (2^13)
  const int un = edge_at(u, g, is64);
  const int vn = edge_at(v, g, is64);
  const float Xu = X[(size_t)t * NNODE + un];
  const float Xv = X[(size_t)t * NNODE + vn];
  const float ad = fabsf(Xu - Xv);
  const float epsp = sigm(theta[0]) * 0.5f;
  const float epsm = 0.5f + sigm(theta[1]) * 0.5f;
  outKp[g] = sigm(RHO_ * (epsp - ad));
  outKm[g] = sigm(RHO_ * (ad - epsm));
}

// ---------------------------------------------------------------------------
// kDiag: forced host-probe failure encoding only (layout/ws sanity).
// ---------------------------------------------------------------------------
__global__ void kDiag(float* __restrict__ outX, int b0, int b1) {
  if (threadIdx.x != 0 || blockIdx.x != 0) return;
  outX[0] = (float)(2048 + 1024 * b0 + 512 * b1);
}

// ---------------------------------------------------------------------------
extern "C" void kernel_launch(void* const* d_in, const int* in_sizes, int n_in,
                              void* d_out, int out_size, void* d_ws, size_t ws_size,
                              hipStream_t stream) {
  const float* logit = (const float*)d_in[0];
  const float* theta = (const float*)d_in[1];
  const int*   u     = (const int*)d_in[2];
  const int*   v     = (const int*)d_in[3];
  const float* sp    = (const float*)d_in[4];
  const float* sm    = (const float*)d_in[5];

  float* outX  = (float*)d_out;                         // [T, N] f32
  float* outKp = outX + (size_t)TSTEPS * NNODE;         // [T, E] f32
  float* outKm = outKp + (size_t)TSTEPS * NEDGE;        // [T, E] f32

  const int b0 = (n_in == 6 &&
                  in_sizes[0] == NNODE && in_sizes[1] == 2 &&
                  in_sizes[2] == TSTEPS * NEDGE && in_sizes[3] == TSTEPS * NEDGE &&
                  in_sizes[4] == TSTEPS * NEDGE && in_sizes[5] == TSTEPS * NEDGE) ? 1 : 0;
  const size_t WS_NEED = (size_t)4 * NNODE * 4 + 64;    // xsA,xsB,dA,dB + flags
  const int b1 = (ws_size >= WS_NEED) ? 1 : 0;
  if (!b0 || !b1) {
    kDiag<<<1, 64, 0, stream>>>(outX, b0, b1);
    return;
  }

  // workspace: xsA | xsB (N f32 each) | dA | dB (N u32 each) | dflags(8) | bar
  char* ws = (char*)d_ws;
  float*    xsA    = (float*)ws;
  float*    xsB    = (float*)(ws + (size_t)NNODE * 4);
  unsigned* dA     = (unsigned*)(ws + (size_t)2 * NNODE * 4);
  unsigned* dB     = (unsigned*)(ws + (size_t)3 * NNODE * 4);
  unsigned* dflags = (unsigned*)(ws + (size_t)4 * NNODE * 4);
  unsigned* bar    = dflags + 4;                        // 2 slots

  k_detect<<<1, 64, 0, stream>>>(u, v, dflags);
  k_init<<<2048, 256, 0, stream>>>(logit, xsA, xsB, dA, dB, bar, outX);
  k_scan<<<KBLK, NTHR, 0, stream>>>(u, v, sp, sm, xsA, xsB, dA, dB,
                                    bar, dflags, outX);
  k_fill<<<(NNODE + 255) / 256, 256, 0, stream>>>(logit, (unsigned*)d_out);
  k_kappa<<<(TSTEPS * NEDGE) / 256, 256, 0, stream>>>(u, v, theta, outX,
                                                      outKp, outKm, dflags);
}

// Round 12
// 1990.079 us; speedup vs baseline: 3.1501x; 3.1501x over previous
//
#include <hip/hip_runtime.h>

// Problem constants (fixed by the reference).
#define TSTEPS 256
#define NNODE  100000
#define NEDGE  8192

constexpr float MU_P  = 0.1f;
constexpr float MU_M  = 0.05f;
constexpr float RHO_  = 16.0f;
constexpr float CLO   = 1e-5f;
constexpr float CHI   = 1.0f - 1e-5f;
constexpr float SCALE = 1048576.0f;          // 2^20 fixed-point for delta
constexpr float INVSC = 1.0f / 1048576.0f;

// f32 sentinel: real X values are positive finite, 0xFFFFFFFF impossible.
#define SENT32 0xFFFFFFFFu

typedef unsigned long long u64;

__device__ __forceinline__ float sigm(float x) {
  return 1.0f / (1.0f + __expf(-x));
}
__device__ __forceinline__ float x0_of(const float* logit, int n) {
  return fminf(fmaxf(sigm(logit[n]), CLO), CHI);
}
__device__ __forceinline__ int edge_at(const int* __restrict__ arr, int idx,
                                       int is64) {
  if (is64) return (int)((const long long*)arr)[idx];
  return arr[idx];
}

// 8-byte atomic pair ops, workgroup scope -> plain cached dwordx2 instructions
// (no L2 bypass; R11 showed agent scope bypasses L2 at huge cost). Stale reads
// are CORRECT in this algorithm (old pair -> combine path), so caching is fine.
__device__ __forceinline__ u64 pload(const u64* p) {
  return __hip_atomic_load(p, __ATOMIC_RELAXED, __HIP_MEMORY_SCOPE_WORKGROUP);
}
__device__ __forceinline__ void pstore(u64* p, u64 v) {
  __hip_atomic_store(p, v, __ATOMIC_RELAXED, __HIP_MEMORY_SCOPE_WORKGROUP);
}

// ---------------------------------------------------------------------------
// k_detect: int32 vs int64 materialization of u/v (runtime-proof either way).
// ---------------------------------------------------------------------------
__global__ void k_detect(const int* __restrict__ u, const int* __restrict__ v,
                         unsigned* __restrict__ dflags) {
  if (threadIdx.x != 0 || blockIdx.x != 0) return;
  const unsigned* a = (const unsigned*)u;
  const unsigned* b = (const unsigned*)v;
  bool i64 = true;
  for (int k = 1; k < 128; k += 2) i64 = i64 && (a[k] == 0u) && (b[k] == 0u);
  dflags[0] = i64 ? 1u : 0u;
}

// ---------------------------------------------------------------------------
// k_init: xs64[n] = {tag=0, clip(sigmoid(logit))}; three delta buffers
// zeroed; output X row 0 = sigmoid(logit) UNCLIPPED f32; X rows 1..T-1 =
// sentinel. Re-runs every call -> deterministic replays.
// ---------------------------------------------------------------------------
__global__ void k_init(const float* __restrict__ logit,
                       u64* __restrict__ xs64,
                       unsigned* __restrict__ d0, unsigned* __restrict__ d1,
                       unsigned* __restrict__ d2,
                       float* __restrict__ outX) {
  const int i = blockIdx.x * blockDim.x + threadIdx.x;
  const int stride = gridDim.x * blockDim.x;

  for (int n = i; n < NNODE; n += stride) {
    xs64[n] = (u64)__float_as_uint(x0_of(logit, n));   // tag 0 in high word
    d0[n] = 0u;
    d1[n] = 0u;
    d2[n] = 0u;
    outX[n] = sigm(logit[n]);            // row 0, unclipped, f32
  }
  unsigned* outX32 = (unsigned*)outX;
  const int total = TSTEPS * NNODE;
  for (int w = NNODE + i; w < total; w += stride) outX32[w] = SENT32;
}

// ---------------------------------------------------------------------------
// k_step (ONE dispatch per timestep t; cross-step visibility = dispatch
// boundary, the 4us-cheap mechanism R9 proved). 2E threads, three jobs each:
//  A (s<E): gather edge (t,s) via lazy x_t; kappa row t; accumulate dcur.
//  B: apply endpoint s of row t-1: val=lazy(node); xs64[node]={t,val};
//     outX[t][node]=val. Duplicate writers store identical bits (benign).
//  C: zero dzero at endpoint s of row t-2 (exactly that buffer's dirty set).
// lazy(n): {tag,val} = xs64[n]; tag==t ? val : clip(val + dprev[n]*2^-20).
// Stale pair -> combine path -> still x_t: correct under ANY cache staleness;
// 8B atomicity only prevents tearing.
// ---------------------------------------------------------------------------
__global__ void k_step(const int* __restrict__ u, const int* __restrict__ v,
                       const float* __restrict__ sp, const float* __restrict__ sm,
                       const float* __restrict__ theta,
                       u64* __restrict__ xs64,
                       unsigned* __restrict__ d0, unsigned* __restrict__ d1,
                       unsigned* __restrict__ d2,
                       float* __restrict__ outX,
                       float* __restrict__ outKp, float* __restrict__ outKm,
                       const unsigned* __restrict__ dflags, int t) {
  const int s = blockIdx.x * blockDim.x + threadIdx.x;   // 0..2*NEDGE-1
  const int is64 = (int)dflags[0];

  unsigned* dbuf[3] = {d0, d1, d2};
  unsigned* dcur  = dbuf[t % 3];
  unsigned* dprev = dbuf[(t + 2) % 3];
  unsigned* dzero = dbuf[(t + 1) % 3];

  const unsigned ttag = (unsigned)t;

  // lazy x_t evaluator
  auto lazy = [&](int n) -> float {
    const u64 a = pload(&xs64[n]);
    const unsigned tag = (unsigned)(a >> 32);
    float val = __uint_as_float((unsigned)a);
    if (tag != ttag) {
      const int acc = (int)dprev[n];
      val = fminf(fmaxf(val + (float)acc * INVSC, CLO), CHI);
    }
    return val;
  };

  // ---- Job A: gather + kappa + accumulate (edges of row t) ----
  if (s < NEDGE) {
    const int e  = t * NEDGE + s;
    const int un = edge_at(u, e, is64);
    const int vn = edge_at(v, e, is64);
    const float xu = lazy(un);
    const float xv = lazy(vn);
    const float d  = xv - xu;               // = -(Xu - Xv)
    const float ad = fabsf(d);
    const float epsp = sigm(theta[0]) * 0.5f;
    const float epsm = 0.5f + sigm(theta[1]) * 0.5f;
    outKp[e] = sigm(RHO_ * (epsp - ad));
    outKm[e] = sigm(RHO_ * (ad - epsm));
    if (t < TSTEPS - 1) {
      const float w  = MU_P * sp[e] - MU_M * sm[e];
      const int   iv = __float2int_rn(w * d * SCALE);
      atomicAdd(&dcur[un], (unsigned)iv);      // HW-coherent RMW (R9-proven)
      atomicAdd(&dcur[vn], (unsigned)(-iv));
    }
  }

  // ---- Job B: apply endpoints of row t-1 -> x_t persisted + outX row t ----
  if (t >= 1) {
    const int e2 = (t - 1) * NEDGE + (s < NEDGE ? s : s - NEDGE);
    const int node = (s < NEDGE) ? edge_at(u, e2, is64) : edge_at(v, e2, is64);
    const float val = lazy(node);
    pstore(&xs64[node], ((u64)ttag << 32) | (u64)__float_as_uint(val));
    outX[(size_t)t * NNODE + node] = val;    // duplicates write same bits
  }

  // ---- Job C: zero dzero at endpoints of row t-2 (ready for step t+1) ----
  if (t >= 2) {
    const int e3 = (t - 2) * NEDGE + (s < NEDGE ? s : s - NEDGE);
    const int node = (s < NEDGE) ? edge_at(u, e3, is64) : edge_at(v, e3, is64);
    dzero[node] = 0u;
  }
}

// ---------------------------------------------------------------------------
// k_fill: resolve sentinels by fill-forward; coalesced per-node columns.
// ---------------------------------------------------------------------------
__global__ void k_fill(const float* __restrict__ logit,
                       unsigned* __restrict__ outX32) {
  const int n = blockIdx.x * blockDim.x + threadIdx.x;
  if (n >= NNODE) return;
  unsigned carry = __float_as_uint(x0_of(logit, n));   // untouched = clip(X0)
  for (int t = 1; t < TSTEPS; ++t) {
    const size_t idx = (size_t)t * NNODE + n;
    const unsigned w = outX32[idx];
    if (w == SENT32) outX32[idx] = carry;
    else             carry = w;
  }
}

// ---------------------------------------------------------------------------
// kDiag: forced host-probe failure encoding only (layout/ws sanity).
// ---------------------------------------------------------------------------
__global__ void kDiag(float* __restrict__ outX, int b0, int b1) {
  if (threadIdx.x != 0 || blockIdx.x != 0) return;
  outX[0] = (float)(2048 + 1024 * b0 + 512 * b1);
}

// ---------------------------------------------------------------------------
extern "C" void kernel_launch(void* const* d_in, const int* in_sizes, int n_in,
                              void* d_out, int out_size, void* d_ws, size_t ws_size,
                              hipStream_t stream) {
  const float* logit = (const float*)d_in[0];
  const float* theta = (const float*)d_in[1];
  const int*   u     = (const int*)d_in[2];
  const int*   v     = (const int*)d_in[3];
  const float* sp    = (const float*)d_in[4];
  const float* sm    = (const float*)d_in[5];

  float* outX  = (float*)d_out;                         // [T, N] f32
  float* outKp = outX + (size_t)TSTEPS * NNODE;         // [T, E] f32
  float* outKm = outKp + (size_t)TSTEPS * NEDGE;        // [T, E] f32

  const int b0 = (n_in == 6 &&
                  in_sizes[0] == NNODE && in_sizes[1] == 2 &&
                  in_sizes[2] == TSTEPS * NEDGE && in_sizes[3] == TSTEPS * NEDGE &&
                  in_sizes[4] == TSTEPS * NEDGE && in_sizes[5] == TSTEPS * NEDGE) ? 1 : 0;
  const size_t WS_NEED = (size_t)NNODE * 8 + (size_t)3 * NNODE * 4 + 64;
  const int b1 = (ws_size >= WS_NEED) ? 1 : 0;
  if (!b0 || !b1) {
    kDiag<<<1, 64, 0, stream>>>(outX, b0, b1);
    return;
  }

  // workspace: xs64 (N u64) | d0 | d1 | d2 (N u32 each) | dflags (8 u32)
  char* ws = (char*)d_ws;
  u64*      xs64   = (u64*)ws;
  unsigned* d0     = (unsigned*)(ws + (size_t)NNODE * 8);
  unsigned* d1     = (unsigned*)(ws + (size_t)NNODE * 8 + (size_t)NNODE * 4);
  unsigned* d2     = (unsigned*)(ws + (size_t)NNODE * 8 + (size_t)2 * NNODE * 4);
  unsigned* dflags = (unsigned*)(ws + (size_t)NNODE * 8 + (size_t)3 * NNODE * 4);

  k_detect<<<1, 64, 0, stream>>>(u, v, dflags);
  k_init<<<2048, 256, 0, stream>>>(logit, xs64, d0, d1, d2, outX);

  for (int t = 0; t < TSTEPS; ++t) {
    k_step<<<(2 * NEDGE) / 256, 256, 0, stream>>>(u, v, sp, sm, theta, xs64,
                                                  d0, d1, d2, outX, outKp,
                                                  outKm, dflags, t);
  }

  k_fill<<<(NNODE + 255) / 256, 256, 0, stream>>>(logit, (unsigned*)d_out);
}

// Round 13
// 1980.108 us; speedup vs baseline: 3.1660x; 1.0050x over previous
//
#include <hip/hip_runtime.h>

// Problem constants (fixed by the reference).
#define TSTEPS 256
#define NNODE  100000
#define NEDGE  8192

constexpr float MU_P  = 0.1f;
constexpr float MU_M  = 0.05f;
constexpr float RHO_  = 16.0f;
constexpr float CLO   = 1e-5f;
constexpr float CHI   = 1.0f - 1e-5f;
constexpr float SCALE = 1048576.0f;          // 2^20 fixed-point for delta
constexpr float INVSC = 1.0f / 1048576.0f;

// f32 sentinel: real X values are positive finite, 0xFFFFFFFF impossible.
#define SENT32 0xFFFFFFFFu

typedef unsigned long long u64;

__device__ __forceinline__ float sigm(float x) {
  return 1.0f / (1.0f + __expf(-x));
}
__device__ __forceinline__ float x0_of(const float* logit, int n) {
  return fminf(fmaxf(sigm(logit[n]), CLO), CHI);
}
__device__ __forceinline__ int edge_at(const int* __restrict__ arr, int idx,
                                       int is64) {
  if (is64) return (int)((const long long*)arr)[idx];
  return arr[idx];
}

// 8-byte atomic pair ops (no tearing); workgroup scope -> plain cached
// dwordx2 (R11 proved agent scope bypasses L2 at ~1.4 GB cost). Stale pairs
// are CORRECT here: old tag -> combine path reproduces the same value.
__device__ __forceinline__ u64 pload(const u64* p) {
  return __hip_atomic_load(p, __ATOMIC_RELAXED, __HIP_MEMORY_SCOPE_WORKGROUP);
}
__device__ __forceinline__ void pstore(u64* p, u64 v) {
  __hip_atomic_store(p, v, __ATOMIC_RELAXED, __HIP_MEMORY_SCOPE_WORKGROUP);
}

// ---------------------------------------------------------------------------
// k_init: state + deltas + output rows init; one thread also runs the
// int32/int64 detection probe (folded k_detect: saves one dispatch).
// Re-runs every call -> deterministic replays.
// ---------------------------------------------------------------------------
__global__ void k_init(const float* __restrict__ logit,
                       const int* __restrict__ u, const int* __restrict__ v,
                       u64* __restrict__ xs64,
                       unsigned* __restrict__ d0, unsigned* __restrict__ d1,
                       unsigned* __restrict__ d2,
                       unsigned* __restrict__ dflags,
                       float* __restrict__ outX) {
  const int i = blockIdx.x * blockDim.x + threadIdx.x;
  const int stride = gridDim.x * blockDim.x;

  if (i == 0) {   // folded detect probe
    const unsigned* a = (const unsigned*)u;
    const unsigned* b = (const unsigned*)v;
    bool i64 = true;
    for (int k = 1; k < 128; k += 2) i64 = i64 && (a[k] == 0u) && (b[k] == 0u);
    dflags[0] = i64 ? 1u : 0u;
  }

  for (int n = i; n < NNODE; n += stride) {
    xs64[n] = (u64)__float_as_uint(x0_of(logit, n));   // tag 0 in high word
    d0[n] = 0u;
    d1[n] = 0u;
    d2[n] = 0u;
    outX[n] = sigm(logit[n]);            // row 0, unclipped, f32
  }
  unsigned* outX32 = (unsigned*)outX;
  const int total = TSTEPS * NNODE;
  for (int w = NNODE + i; w < total; w += stride) outX32[w] = SENT32;
}

// ---------------------------------------------------------------------------
// k_step (ONE dispatch per timestep t; cross-step visibility = the proven
// dispatch boundary). 2E threads, three slim jobs (kappa REMOVED -> post-pass):
//  A (s<E, t<T-1): gather edge (t,s) via lazy x_t; accumulate fixed-point
//                  delta into dcur.
//  B (t>=1): apply endpoint s of row t-1: val=lazy(node); xs64[node]={t,val};
//            outX[t][node]=val. Duplicates store identical bits (benign).
//  C (t>=2): zero dzero at endpoint s of row t-2 (that buffer's dirty set).
// lazy(n): {tag,val}=xs64[n]; tag==t ? val : clip(val + dprev[n]*2^-20).
// ---------------------------------------------------------------------------
__global__ void k_step(const int* __restrict__ u, const int* __restrict__ v,
                       const float* __restrict__ sp, const float* __restrict__ sm,
                       u64* __restrict__ xs64,
                       unsigned* __restrict__ d0, unsigned* __restrict__ d1,
                       unsigned* __restrict__ d2,
                       float* __restrict__ outX,
                       const unsigned* __restrict__ dflags, int t) {
  const int s = blockIdx.x * blockDim.x + threadIdx.x;   // 0..2*NEDGE-1
  const int is64 = (int)dflags[0];

  unsigned* dbuf[3] = {d0, d1, d2};
  unsigned* dcur  = dbuf[t % 3];
  unsigned* dprev = dbuf[(t + 2) % 3];
  unsigned* dzero = dbuf[(t + 1) % 3];

  const unsigned ttag = (unsigned)t;

  auto lazy = [&](int n) -> float {
    const u64 a = pload(&xs64[n]);
    const unsigned tag = (unsigned)(a >> 32);
    float val = __uint_as_float((unsigned)a);
    if (tag != ttag) {
      const int acc = (int)dprev[n];
      val = fminf(fmaxf(val + (float)acc * INVSC, CLO), CHI);
    }
    return val;
  };

  // ---- Job A: gather + accumulate (edges of row t); kappa moved out ----
  if (s < NEDGE && t < TSTEPS - 1) {
    const int e  = t * NEDGE + s;
    const int un = edge_at(u, e, is64);
    const int vn = edge_at(v, e, is64);
    const float xu = lazy(un);
    const float xv = lazy(vn);
    const float w  = MU_P * sp[e] - MU_M * sm[e];
    const int   iv = __float2int_rn(w * (xv - xu) * SCALE);
    atomicAdd(&dcur[un], (unsigned)iv);      // HW-coherent RMW (R9/R12-proven)
    atomicAdd(&dcur[vn], (unsigned)(-iv));
  }

  // ---- Job B: apply endpoints of row t-1 -> x_t persisted + outX row t ----
  if (t >= 1) {
    const int e2 = (t - 1) * NEDGE + (s < NEDGE ? s : s - NEDGE);
    const int node = (s < NEDGE) ? edge_at(u, e2, is64) : edge_at(v, e2, is64);
    const float val = lazy(node);
    pstore(&xs64[node], ((u64)ttag << 32) | (u64)__float_as_uint(val));
    outX[(size_t)t * NNODE + node] = val;    // duplicates write same bits
  }

  // ---- Job C: zero dzero at endpoints of row t-2 (ready for step t+1) ----
  if (t >= 2) {
    const int e3 = (t - 2) * NEDGE + (s < NEDGE ? s : s - NEDGE);
    const int node = (s < NEDGE) ? edge_at(u, e3, is64) : edge_at(v, e3, is64);
    dzero[node] = 0u;
  }
}

// ---------------------------------------------------------------------------
// k_fill: resolve sentinels by fill-forward; coalesced per-node columns.
// ---------------------------------------------------------------------------
__global__ void k_fill(const float* __restrict__ logit,
                       unsigned* __restrict__ outX32) {
  const int n = blockIdx.x * blockDim.x + threadIdx.x;
  if (n >= NNODE) return;
  unsigned carry = __float_as_uint(x0_of(logit, n));   // untouched = clip(X0)
  for (int t = 1; t < TSTEPS; ++t) {
    const size_t idx = (size_t)t * NNODE + n;
    const unsigned w = outX32[idx];
    if (w == SENT32) outX32[idx] = carry;
    else             carry = w;
  }
}

// ---------------------------------------------------------------------------
// k_kappa: massively-parallel kappa over ALL T*E edges from the filled dense
// X (f32 exact scan values; R11-proven). e varies fastest -> X row t stays
// L2-resident while its 8192 edges process.
// ---------------------------------------------------------------------------
__global__ void k_kappa(const int* __restrict__ u, const int* __restrict__ v,
                        const float* __restrict__ theta,
                        const float* __restrict__ X,
                        float* __restrict__ outKp, float* __restrict__ outKm,
                        const unsigned* __restrict__ dflags) {
  const int g = blockIdx.x * blockDim.x + threadIdx.x;   // 0..T*E-1
  const int is64 = (int)dflags[0];
  const int t  = g >> 13;                                // / NEDGE (2^13)
  const int un = edge_at(u, g, is64);
  const int vn = edge_at(v, g, is64);
  const float Xu = X[(size_t)t * NNODE + un];
  const float Xv = X[(size_t)t * NNODE + vn];
  const float ad = fabsf(Xu - Xv);
  const float epsp = sigm(theta[0]) * 0.5f;
  const float epsm = 0.5f + sigm(theta[1]) * 0.5f;
  outKp[g] = sigm(RHO_ * (epsp - ad));
  outKm[g] = sigm(RHO_ * (ad - epsm));
}

// ---------------------------------------------------------------------------
// kDiag: forced host-probe failure encoding only (layout/ws sanity).
// ---------------------------------------------------------------------------
__global__ void kDiag(float* __restrict__ outX, int b0, int b1) {
  if (threadIdx.x != 0 || blockIdx.x != 0) return;
  outX[0] = (float)(2048 + 1024 * b0 + 512 * b1);
}

// ---------------------------------------------------------------------------
extern "C" void kernel_launch(void* const* d_in, const int* in_sizes, int n_in,
                              void* d_out, int out_size, void* d_ws, size_t ws_size,
                              hipStream_t stream) {
  const float* logit = (const float*)d_in[0];
  const float* theta = (const float*)d_in[1];
  const int*   u     = (const int*)d_in[2];
  const int*   v     = (const int*)d_in[3];
  const float* sp    = (const float*)d_in[4];
  const float* sm    = (const float*)d_in[5];

  float* outX  = (float*)d_out;                         // [T, N] f32
  float* outKp = outX + (size_t)TSTEPS * NNODE;         // [T, E] f32
  float* outKm = outKp + (size_t)TSTEPS * NEDGE;        // [T, E] f32

  const int b0 = (n_in == 6 &&
                  in_sizes[0] == NNODE && in_sizes[1] == 2 &&
                  in_sizes[2] == TSTEPS * NEDGE && in_sizes[3] == TSTEPS * NEDGE &&
                  in_sizes[4] == TSTEPS * NEDGE && in_sizes[5] == TSTEPS * NEDGE) ? 1 : 0;
  const size_t WS_NEED = (size_t)NNODE * 8 + (size_t)3 * NNODE * 4 + 64;
  const int b1 = (ws_size >= WS_NEED) ? 1 : 0;
  if (!b0 || !b1) {
    kDiag<<<1, 64, 0, stream>>>(outX, b0, b1);
    return;
  }

  // workspace: xs64 (N u64) | d0 | d1 | d2 (N u32 each) | dflags (8 u32)
  char* ws = (char*)d_ws;
  u64*      xs64   = (u64*)ws;
  unsigned* d0     = (unsigned*)(ws + (size_t)NNODE * 8);
  unsigned* d1     = (unsigned*)(ws + (size_t)NNODE * 8 + (size_t)NNODE * 4);
  unsigned* d2     = (unsigned*)(ws + (size_t)NNODE * 8 + (size_t)2 * NNODE * 4);
  unsigned* dflags = (unsigned*)(ws + (size_t)NNODE * 8 + (size_t)3 * NNODE * 4);

  k_init<<<2048, 256, 0, stream>>>(logit, u, v, xs64, d0, d1, d2, dflags, outX);

  for (int t = 0; t < TSTEPS; ++t) {
    k_step<<<(2 * NEDGE) / 256, 256, 0, stream>>>(u, v, sp, sm, xs64,
                                                  d0, d1, d2, outX,
                                                  dflags, t);
  }

  k_fill<<<(NNODE + 255) / 256, 256, 0, stream>>>(logit, (unsigned*)d_out);
  k_kappa<<<(TSTEPS * NEDGE) / 256, 256, 0, stream>>>(u, v, theta, outX,
                                                      outKp, outKm, dflags);
}